// Round 7
// baseline (5676.604 us; speedup 1.0000x reference)
//
#include <hip/hip_runtime.h>
#include <stdint.h>

#define NN 384
#define NE 3456
#define NLb 32
#define F 64
#define KD 32

typedef short shortx8 __attribute__((ext_vector_type(8)));
typedef float floatx4 __attribute__((ext_vector_type(4)));

__device__ __forceinline__ float sigm(float v) { return 1.0f / (1.0f + __expf(-v)); }
__device__ __forceinline__ float tanhf_(float v) {
    float x = fminf(fmaxf(v, -15.0f), 15.0f);
    float e = __expf(2.0f * x);
    return (e - 1.0f) / (e + 1.0f);
}
__device__ __forceinline__ uint16_t f2bf(float f) {
    uint32_t u = __float_as_uint(f);
    uint32_t r = (u + 0x7fffu + ((u >> 16) & 1u)) >> 16;
    return (uint16_t)r;
}
__device__ __forceinline__ float bf2f(uint16_t h) {
    return __uint_as_float((uint32_t)h << 16);
}

__global__ void k_zero(float* p, int n) {
    int i = blockIdx.x * 256 + threadIdx.x;
    int st = gridDim.x * 256;
    for (; i < n; i += st) p[i] = 0.0f;
}

__global__ void k_build(const int* __restrict__ e1, const int* __restrict__ e2,
                        float* __restrict__ C, float* __restrict__ Adj) {
    int t = blockIdx.x * 256 + threadIdx.x;
    if (t >= 2 * NE) return;
    int g = t / NE, e = t % NE;
    const int* ei = g ? e2 : e1;
    int s = ei[e], d = ei[NE + e];
    atomicAdd(&C[(size_t)g * NN * NN + d * NN + s], 1.0f);
    if (e < NE - NN) Adj[(size_t)g * NN * NN + s * NN + d] = 1.0f;
}

__global__ void k_degx(const float* __restrict__ f1, const float* __restrict__ f2,
                       const float* __restrict__ Adj, float* __restrict__ X) {
    int g = blockIdx.y;
    int s = blockIdx.x * 64 + threadIdx.x;
    const float* feats = g ? f2 : f1;
    const float* A = Adj + (size_t)g * NN * NN;
    float* Xg = X + (size_t)g * NN * 33;
    float deg = 0.0f;
    for (int d = 0; d < NN; d++) deg += A[s * NN + d];
    for (int c = 0; c < NLb; c++) Xg[s * 33 + c] = feats[s * NLb + c];
    Xg[s * 33 + 32] = deg;
}

__global__ __launch_bounds__(64)
void k_lin0(const float* __restrict__ X, const float* __restrict__ w1,
            const float* __restrict__ b1, const float* __restrict__ w2,
            const float* __restrict__ b2, float* __restrict__ HS) {
    __shared__ float tl[64];
    int g = blockIdx.y, m = blockIdx.x, n = threadIdx.x;
    const float* Xr = X + (size_t)g * NN * 33 + m * 33;
    float t = b1[n];
#pragma unroll
    for (int k = 0; k < 33; k++) t += Xr[k] * w1[k * F + n];
    t = fmaxf(t, 0.0f);
    tl[n] = t;
    __syncthreads();
    float o = b2[n];
#pragma unroll 4
    for (int k = 0; k < F; k++) o += tl[k] * w2[k * F + n];
    HS[(size_t)g * (6 * NN * F) + m * F + n] = o;
}

__global__ __launch_bounds__(64)
void k_gin(const float* __restrict__ C, const float* __restrict__ hin, int hGs,
           const float* __restrict__ gw1, const float* __restrict__ gb1,
           const float* __restrict__ gw2, const float* __restrict__ gb2,
           const float* __restrict__ geps, int li,
           float* __restrict__ zout, int oGs) {
    __shared__ float zl[64], tl[64];
    int g = blockIdx.y, m = blockIdx.x, n = threadIdx.x;
    const float* Crow = C + (size_t)g * NN * NN + (size_t)m * NN;
    const float* h = hin + (size_t)g * hGs;
    float acc = 0.0f;
#pragma unroll 4
    for (int k = 0; k < NN; k++) acc += Crow[k] * h[k * F + n];
    acc += (1.0f + geps[li]) * h[m * F + n];
    zl[n] = acc;
    __syncthreads();
    const float* W1 = gw1 + (size_t)li * F * F;
    const float* W2 = gw2 + (size_t)li * F * F;
    float t = gb1[li * F + n];
#pragma unroll 4
    for (int k = 0; k < F; k++) t += zl[k] * W1[k * F + n];
    t = fmaxf(t, 0.0f);
    tl[n] = t;
    __syncthreads();
    float o = gb2[li * F + n];
#pragma unroll 4
    for (int k = 0; k < F; k++) o += tl[k] * W2[k * F + n];
    zout[(size_t)g * oGs + m * F + n] = o;
}

__global__ __launch_bounds__(256)
void k_bn(float* __restrict__ hsb, int hsGs, float* __restrict__ hbuf, int hGs,
          const float* __restrict__ gamma, const float* __restrict__ beta) {
    __shared__ float red[4][64];
    int g = blockIdx.x;
    float* z = hsb + (size_t)g * hsGs;
    float* h = hbuf + (size_t)g * hGs;
    int c = threadIdx.x & 63, rq = threadIdx.x >> 6;
    int r0 = rq * 96;
    float s = 0.0f;
    for (int r = r0; r < r0 + 96; r++) s += z[r * F + c];
    red[rq][c] = s;
    __syncthreads();
    float mu = (red[0][c] + red[1][c] + red[2][c] + red[3][c]) * (1.0f / NN);
    __syncthreads();
    float v = 0.0f;
    for (int r = r0; r < r0 + 96; r++) { float d = z[r * F + c] - mu; v += d * d; }
    red[rq][c] = v;
    __syncthreads();
    float var = (red[0][c] + red[1][c] + red[2][c] + red[3][c]) * (1.0f / NN);
    float is = rsqrtf(var + 1e-5f);
    float ga = gamma[c], be = beta[c];
    for (int r = r0; r < r0 + 96; r++) {
        float zn = (z[r * F + c] - mu) * is * ga + be;
        z[r * F + c] = zn;
        h[r * F + c] = fmaxf(zn, 0.0f);
    }
}

// f32 HS (graph 1 only) -> bf16 hi/lo
__global__ void k_cvt2(const float* __restrict__ HS, uint16_t* __restrict__ hhi,
                       uint16_t* __restrict__ hlo) {
    int idx = blockIdx.x * 256 + threadIdx.x;
    if (idx >= 6 * NN * F) return;
    float v = HS[idx];
    uint16_t h = f2bf(v);
    hhi[idx] = h;
    hlo[idx] = f2bf(v - bf2f(h));
}

__global__ __launch_bounds__(64)
void k_gedT2(const float* __restrict__ ged, uint16_t* __restrict__ ghi,
             uint16_t* __restrict__ glo) {
    __shared__ float t[64 * 65];
    int lk = blockIdx.x, lane = threadIdx.x;
    const float* src = ged + (size_t)lk * 4096;
    for (int d = 0; d < 64; d++) t[lane * 65 + d] = src[d * 64 + lane];
    __syncthreads();
    for (int e = 0; e < 64; e++) {
        float v = t[e * 65 + lane];
        uint16_t h = f2bf(v);
        ghi[(size_t)lk * 4096 + e * 64 + lane] = h;
        glo[(size_t)lk * 4096 + e * 64 + lane] = f2bf(v - bf2f(h));
    }
}

// wpack (f32):
// [0    wih 3072][3072 whh 3072][6144 wawT 1024][7168 vwT 1024]
// [8192 bR 32][8224 bZ 32][8256 biN 32][8288 bhN 32]
// [8320 wab 32][8352 vat 32][8384 vb 32]   total 8416
__global__ __launch_bounds__(256)
void k_wprep4(const float* __restrict__ wih, const float* __restrict__ whh,
              const float* __restrict__ waw, const float* __restrict__ vw,
              const float* __restrict__ bih, const float* __restrict__ bhh,
              const float* __restrict__ wab, const float* __restrict__ vat,
              const float* __restrict__ vb, float* __restrict__ wp) {
    int t = threadIdx.x;
    for (int idx = t; idx < 3072; idx += 256) {
        wp[idx] = wih[idx];
        wp[3072 + idx] = whh[idx];
    }
    for (int idx = t; idx < 1024; idx += 256) {
        int c = idx >> 5, k = idx & 31;
        wp[6144 + idx] = waw[k * 32 + c];
        wp[7168 + idx] = vw[k * 32 + c];
    }
    if (t < 64) wp[8192 + t] = bih[t] + bhh[t];
    if (t < 32) {
        wp[8256 + t] = bih[64 + t];
        wp[8288 + t] = bhh[64 + t];
        wp[8320 + t] = wab[t];
        wp[8352 + t] = vat[t];
        wp[8384 + t] = vb[t];
    }
}

// T1f[l,i,n=k*64+e] = sum_d gedT[l,n,d]*h1[l,i,d]  (hi/lo MFMA, f32 out)
__global__ __launch_bounds__(256)
void k_t1m2(const uint16_t* __restrict__ gThi, const uint16_t* __restrict__ gTlo,
            const uint16_t* __restrict__ hbhi, const uint16_t* __restrict__ hblo,
            float* __restrict__ T1f) {
    int l = blockIdx.z;
    int w = threadIdx.x >> 6, lane = threadIdx.x & 63;
    int nb = blockIdx.x * 128 + (w >> 1) * 64;
    int ib = blockIdx.y * 128 + (w & 1) * 64;
    int lr = lane & 15, lq = lane >> 4;
    const uint16_t* gah = gThi + (size_t)l * 2048 * 64;
    const uint16_t* gal = gTlo + (size_t)l * 2048 * 64;
    const uint16_t* gbh = hbhi + (size_t)l * NN * F;
    const uint16_t* gbl = hblo + (size_t)l * NN * F;
    shortx8 Ah[4][2], Al[4][2];
#pragma unroll
    for (int s = 0; s < 4; s++)
#pragma unroll
        for (int ks = 0; ks < 2; ks++) {
            size_t off = (size_t)(nb + s * 16 + lr) * 64 + ks * 32 + lq * 8;
            Ah[s][ks] = *reinterpret_cast<const shortx8*>(gah + off);
            Al[s][ks] = *reinterpret_cast<const shortx8*>(gal + off);
        }
#pragma unroll
    for (int si = 0; si < 4; si++) {
        shortx8 Bh[2], Bl[2];
#pragma unroll
        for (int ks = 0; ks < 2; ks++) {
            size_t off = (size_t)(ib + si * 16 + lr) * 64 + ks * 32 + lq * 8;
            Bh[ks] = *reinterpret_cast<const shortx8*>(gbh + off);
            Bl[ks] = *reinterpret_cast<const shortx8*>(gbl + off);
        }
#pragma unroll
        for (int sn = 0; sn < 4; sn++) {
            floatx4 a = (floatx4){0.f, 0.f, 0.f, 0.f};
#pragma unroll
            for (int ks = 0; ks < 2; ks++) {
                a = __builtin_amdgcn_mfma_f32_16x16x32_bf16(Ah[sn][ks], Bh[ks], a, 0, 0, 0);
                a = __builtin_amdgcn_mfma_f32_16x16x32_bf16(Ah[sn][ks], Bl[ks], a, 0, 0, 0);
                a = __builtin_amdgcn_mfma_f32_16x16x32_bf16(Al[sn][ks], Bh[ks], a, 0, 0, 0);
            }
            size_t addr = ((size_t)l * NN + (ib + si * 16 + lr)) * 2048 + (nb + sn * 16 + lq * 4);
            *reinterpret_cast<floatx4*>(T1f + addr) = a;
        }
    }
}

#define DOT4(W, A, B4) ((A)[4*(B4)+0]*(W)[0] + (A)[4*(B4)+1]*(W)[1] + \
                        (A)[4*(B4)+2]*(W)[2] + (A)[4*(B4)+3]*(W)[3])

// Block = 256 threads = 256 consecutive pairs (spans <=2 i values); grid 576.
// Per thread: 1 pair, all state in registers, no LDS h-mirror (GRU gates all
// read h_old -> compute hnew[] fully unrolled, then copy).
__global__ __launch_bounds__(256, 3)
void k_mega8(const float* __restrict__ T1f, const float* __restrict__ HS2,
             const float* __restrict__ wpack,
             const float* __restrict__ q1w, const float* __restrict__ q1b,
             const float* __restrict__ q2w, const float* __restrict__ q2b,
             const float* __restrict__ kw, const float* __restrict__ kb,
             float* __restrict__ out) {
    __shared__ float wl[8416];
    __shared__ float t1l[2][2048];
    const int TX = threadIdx.x;
    const int p0 = blockIdx.x * 256;
    const int p = p0 + TX;
    const int i = p / NN;
    const int j = p - i * NN;
    const int i0 = p0 / NN;
    const float* t1p = t1l[i - i0];   // wave-uniform (384 % 64 == 0)

    for (int idx = TX; idx < 8416; idx += 256) wl[idx] = wpack[idx];

#define FILL_T1(LL) do {                                                       \
    __syncthreads();                                                           \
    _Pragma("unroll")                                                          \
    for (int t = 0; t < 2; t++) {                                              \
        int it = i0 + t; if (it > NN - 1) it = NN - 1;                         \
        const float4* srcp = reinterpret_cast<const float4*>(                  \
            T1f + ((size_t)(LL) * NN + it) * 2048);                            \
        for (int idx = TX; idx < 512; idx += 256)                              \
            reinterpret_cast<float4*>(t1l[t])[idx] = srcp[idx];                \
    }                                                                          \
    __syncthreads();                                                           \
} while (0)

#define COMPUTE_X8(LL) do {                                                    \
    _Pragma("unroll") for (int k = 0; k < KD; k++) x[k] = 0.0f;                \
    const float4* hp = reinterpret_cast<const float4*>(                        \
        HS2 + ((size_t)(LL) * NN + j) * 64);                                   \
    _Pragma("unroll 2")                                                        \
    for (int eb = 0; eb < 16; eb++) {                                          \
        float4 a4 = hp[eb];                                                    \
        _Pragma("unroll") for (int k = 0; k < KD; k++) {                       \
            floatx4 t4 = *reinterpret_cast<const floatx4*>(t1p + k * 64 + eb * 4); \
            x[k] += t4[0]*a4.x + t4[1]*a4.y + t4[2]*a4.z + t4[3]*a4.w;         \
        }                                                                      \
    }                                                                          \
} while (0)

    float h[KD], pacc[KD];
#pragma unroll
    for (int k = 0; k < KD; k++) { h[k] = 0.0f; pacc[k] = 0.0f; }
    float sm = -1e30f, sden = 0.0f;

    // ================= phase A: GRU + layer attention =================
#pragma unroll 1
    for (int l = 0; l < 6; l++) {
        FILL_T1(l);
        float x[KD];
        COMPUTE_X8(l);
        float hnew[KD];
#pragma unroll
        for (int g = 0; g < KD; g++) {
            const floatx4* wiR = reinterpret_cast<const floatx4*>(wl + g * 32);
            const floatx4* wiZ = reinterpret_cast<const floatx4*>(wl + 1024 + g * 32);
            const floatx4* wiN = reinterpret_cast<const floatx4*>(wl + 2048 + g * 32);
            const floatx4* whR = reinterpret_cast<const floatx4*>(wl + 3072 + g * 32);
            const floatx4* whZ = reinterpret_cast<const floatx4*>(wl + 4096 + g * 32);
            const floatx4* whN = reinterpret_cast<const floatx4*>(wl + 5120 + g * 32);
            float ir = 0, iz = 0, in2 = 0, hr = 0, hz = 0, hn = 0;
#pragma unroll
            for (int k4 = 0; k4 < 8; k4++) {
                floatx4 w;
                w = wiR[k4]; ir  += DOT4(w, x, k4);
                w = wiZ[k4]; iz  += DOT4(w, x, k4);
                w = wiN[k4]; in2 += DOT4(w, x, k4);
                w = whR[k4]; hr  += DOT4(w, h, k4);
                w = whZ[k4]; hz  += DOT4(w, h, k4);
                w = whN[k4]; hn  += DOT4(w, h, k4);
            }
            float r  = sigm(ir + hr + wl[8192 + g]);
            float zg = sigm(iz + hz + wl[8224 + g]);
            float ng = tanhf_(in2 + wl[8256 + g] + r * (hn + wl[8288 + g]));
            hnew[g] = (1.0f - zg) * ng + zg * h[g];
        }
#pragma unroll
        for (int k = 0; k < KD; k++) h[k] = hnew[k];
        // attention score
        float sc = 0.0f;
#pragma unroll 2
        for (int c = 0; c < KD; c++) {
            const floatx4* wr = reinterpret_cast<const floatx4*>(wl + 6144 + c * 32);
            float t = wl[8320 + c];
#pragma unroll
            for (int k4 = 0; k4 < 8; k4++) {
                floatx4 w = wr[k4];
                t += DOT4(w, h, k4);
            }
            sc += tanhf_(t) * wl[8352 + c];
        }
        float nm = fmaxf(sm, sc);
        float eo = __expf(sm - nm), en = __expf(sc - nm);
        sden = sden * eo + en; sm = nm;
#pragma unroll
        for (int k = 0; k < KD; k++) pacc[k] = pacc[k] * eo + en * h[k];
    }

    // ---------------- pattern -> q -> qk ----------------
    float qk[KD], qd;
    {
        float inv = 1.0f / sden;
#pragma unroll
        for (int k = 0; k < KD; k++) pacc[k] *= inv;
        float t1r[KD];
#pragma unroll
        for (int c = 0; c < KD; c++) {
            float t = q1b[c];
#pragma unroll
            for (int k = 0; k < KD; k++) t += pacc[k] * q1w[k * KD + c];
            t1r[c] = fmaxf(t, 0.0f);
        }
        float q[KD];
#pragma unroll
        for (int c = 0; c < KD; c++) {
            float t = q2b[c];
#pragma unroll
            for (int k = 0; k < KD; k++) t += t1r[k] * q2w[k * KD + c];
            q[c] = t;
        }
        qd = 0.0f;
#pragma unroll
        for (int c = 0; c < KD; c++) qd += q[c] * kb[c];
#pragma unroll
        for (int k = 0; k < KD; k++) {
            float t = 0.0f;
#pragma unroll
            for (int c = 0; c < KD; c++) t += q[c] * kw[k * KD + c];
            qk[k] = t;
        }
    }

    // ================= phase B: scores + context =================
    float ctx[KD];
#pragma unroll
    for (int k = 0; k < KD; k++) ctx[k] = 0.0f;
    float s2m = -1e30f, s2d = 0.0f;
#pragma unroll 1
    for (int l = 0; l < 6; l++) {
        FILL_T1(l);
        float x[KD];
        COMPUTE_X8(l);
        float s = qd;
#pragma unroll
        for (int k = 0; k < KD; k++) s += x[k] * qk[k];
        s *= 0.17677669529663687f;
        float nm = fmaxf(s2m, s);
        float eo = __expf(s2m - nm), en = __expf(s - nm);
        s2d = s2d * eo + en; s2m = nm;
#pragma unroll 2
        for (int c = 0; c < KD; c++) {
            const floatx4* vr = reinterpret_cast<const floatx4*>(wl + 7168 + c * 32);
            float vc = wl[8384 + c];
#pragma unroll
            for (int k4 = 0; k4 < 8; k4++) {
                floatx4 w = vr[k4];
                vc += DOT4(w, x, k4);
            }
            ctx[c] = ctx[c] * eo + en * vc;
        }
    }
    float invd = 1.0f / s2d;
    float* op = out + ((size_t)i * NN + j) * KD;
#pragma unroll
    for (int k = 0; k < KD; k += 4) {
        float4 w4;
        w4.x = ctx[k] * invd; w4.y = ctx[k + 1] * invd;
        w4.z = ctx[k + 2] * invd; w4.w = ctx[k + 3] * invd;
        *reinterpret_cast<float4*>(op + k) = w4;
    }
#undef FILL_T1
#undef COMPUTE_X8
}

extern "C" void kernel_launch(void* const* d_in, const int* in_sizes, int n_in,
                              void* d_out, int out_size, void* d_ws, size_t ws_size,
                              hipStream_t stream) {
    const float* f1   = (const float*)d_in[0];
    const float* f2   = (const float*)d_in[1];
    const float* l0w1 = (const float*)d_in[2];
    const float* l0b1 = (const float*)d_in[3];
    const float* l0w2 = (const float*)d_in[4];
    const float* l0b2 = (const float*)d_in[5];
    const float* geps = (const float*)d_in[6];
    const float* gw1  = (const float*)d_in[7];
    const float* gb1  = (const float*)d_in[8];
    const float* gw2  = (const float*)d_in[9];
    const float* gb2  = (const float*)d_in[10];
    const float* gga  = (const float*)d_in[11];
    const float* gbe  = (const float*)d_in[12];
    const float* ged  = (const float*)d_in[13];
    const float* wih  = (const float*)d_in[14];
    const float* whh  = (const float*)d_in[15];
    const float* bih  = (const float*)d_in[16];
    const float* bhh  = (const float*)d_in[17];
    const float* waw  = (const float*)d_in[18];
    const float* wab  = (const float*)d_in[19];
    const float* vat  = (const float*)d_in[20];
    const float* q1w  = (const float*)d_in[21];
    const float* q1b  = (const float*)d_in[22];
    const float* q2w  = (const float*)d_in[23];
    const float* q2b  = (const float*)d_in[24];
    const float* kw   = (const float*)d_in[25];
    const float* kb   = (const float*)d_in[26];
    const float* vw   = (const float*)d_in[27];
    const float* vb   = (const float*)d_in[28];
    const int*   e1   = (const int*)d_in[29];
    const int*   e2   = (const int*)d_in[30];

    // ---- workspace layout ----
    float* C     = (float*)d_ws;                        // 2*NN*NN
    float* Adj   = C + (size_t)2 * NN * NN;
    float* X     = Adj + (size_t)2 * NN * NN;           // 2*NN*33
    float* H     = X + (size_t)2 * NN * 33;             // 2*NN*F
    float* HS    = H + (size_t)2 * NN * F;              // [2][6][NN][F]
    float* T1f   = HS + (size_t)2 * 6 * NN * F;         // 6*NN*2048
    float* wpack = T1f + (size_t)6 * NN * 2048;         // 8416
    uint16_t* hbhi = (uint16_t*)(wpack + 8448);         // 6*NN*F
    uint16_t* hblo = hbhi + (size_t)6 * NN * F;
    uint16_t* gThi = hblo + (size_t)6 * NN * F;         // 6*2048*64
    uint16_t* gTlo = gThi + (size_t)6 * 2048 * 64;
    float* out = (float*)d_out;

    const int GHS = 6 * NN * F;
    const int GH  = NN * F;

    k_zero<<<576, 256, 0, stream>>>(C, 4 * NN * NN);
    k_build<<<(2 * NE + 255) / 256, 256, 0, stream>>>(e1, e2, C, Adj);
    k_degx<<<dim3(6, 2), 64, 0, stream>>>(f1, f2, Adj, X);
    k_lin0<<<dim3(NN, 2), 64, 0, stream>>>(X, l0w1, l0b1, l0w2, l0b2, HS);
    for (int li = 0; li < 5; li++) {
        const float* hp = (li == 0) ? HS : H;
        int hGs = (li == 0) ? GHS : GH;
        k_gin<<<dim3(NN, 2), 64, 0, stream>>>(C, hp, hGs, gw1, gb1, gw2, gb2,
                                              geps, li, HS + (li + 1) * GH, GHS);
        k_bn<<<2, 256, 0, stream>>>(HS + (li + 1) * GH, GHS, H, GH,
                                    gga + li * F, gbe + li * F);
    }
    k_cvt2<<<(6 * NN * F + 255) / 256, 256, 0, stream>>>(HS, hbhi, hblo);
    k_gedT2<<<6 * KD, 64, 0, stream>>>(ged, gThi, gTlo);
    k_wprep4<<<1, 256, 0, stream>>>(wih, whh, waw, vw, bih, bhh, wab, vat, vb, wpack);
    k_t1m2<<<dim3(16, 3, 6), 256, 0, stream>>>(gThi, gTlo, hbhi, hblo, T1f);
    k_mega8<<<dim3(576), 256, 0, stream>>>(T1f, HS + GHS, wpack,
                                           q1w, q1b, q2w, q2b, kw, kb, out);
}

// Round 8
// 3854.490 us; speedup vs baseline: 1.4727x; 1.4727x over previous
//
#include <hip/hip_runtime.h>
#include <stdint.h>

#define NN 384
#define NE 3456
#define NLb 32
#define F 64
#define KD 32

typedef short shortx8 __attribute__((ext_vector_type(8)));
typedef float floatx4 __attribute__((ext_vector_type(4)));

__device__ __forceinline__ float sigm(float v) { return 1.0f / (1.0f + __expf(-v)); }
__device__ __forceinline__ float tanhf_(float v) {
    float x = fminf(fmaxf(v, -15.0f), 15.0f);
    float e = __expf(2.0f * x);
    return (e - 1.0f) / (e + 1.0f);
}
__device__ __forceinline__ uint16_t f2bf(float f) {
    uint32_t u = __float_as_uint(f);
    uint32_t r = (u + 0x7fffu + ((u >> 16) & 1u)) >> 16;
    return (uint16_t)r;
}
__device__ __forceinline__ float bf2f(uint16_t h) {
    return __uint_as_float((uint32_t)h << 16);
}

__global__ void k_zero(float* p, int n) {
    int i = blockIdx.x * 256 + threadIdx.x;
    int st = gridDim.x * 256;
    for (; i < n; i += st) p[i] = 0.0f;
}

__global__ void k_build(const int* __restrict__ e1, const int* __restrict__ e2,
                        float* __restrict__ C, float* __restrict__ Adj) {
    int t = blockIdx.x * 256 + threadIdx.x;
    if (t >= 2 * NE) return;
    int g = t / NE, e = t % NE;
    const int* ei = g ? e2 : e1;
    int s = ei[e], d = ei[NE + e];
    atomicAdd(&C[(size_t)g * NN * NN + d * NN + s], 1.0f);
    if (e < NE - NN) Adj[(size_t)g * NN * NN + s * NN + d] = 1.0f;
}

__global__ void k_degx(const float* __restrict__ f1, const float* __restrict__ f2,
                       const float* __restrict__ Adj, float* __restrict__ X) {
    int g = blockIdx.y;
    int s = blockIdx.x * 64 + threadIdx.x;
    const float* feats = g ? f2 : f1;
    const float* A = Adj + (size_t)g * NN * NN;
    float* Xg = X + (size_t)g * NN * 33;
    float deg = 0.0f;
    for (int d = 0; d < NN; d++) deg += A[s * NN + d];
    for (int c = 0; c < NLb; c++) Xg[s * 33 + c] = feats[s * NLb + c];
    Xg[s * 33 + 32] = deg;
}

__global__ __launch_bounds__(64)
void k_lin0(const float* __restrict__ X, const float* __restrict__ w1,
            const float* __restrict__ b1, const float* __restrict__ w2,
            const float* __restrict__ b2, float* __restrict__ HS) {
    __shared__ float tl[64];
    int g = blockIdx.y, m = blockIdx.x, n = threadIdx.x;
    const float* Xr = X + (size_t)g * NN * 33 + m * 33;
    float t = b1[n];
#pragma unroll
    for (int k = 0; k < 33; k++) t += Xr[k] * w1[k * F + n];
    t = fmaxf(t, 0.0f);
    tl[n] = t;
    __syncthreads();
    float o = b2[n];
#pragma unroll 4
    for (int k = 0; k < F; k++) o += tl[k] * w2[k * F + n];
    HS[(size_t)g * (6 * NN * F) + m * F + n] = o;
}

__global__ __launch_bounds__(64)
void k_gin(const float* __restrict__ C, const float* __restrict__ hin, int hGs,
           const float* __restrict__ gw1, const float* __restrict__ gb1,
           const float* __restrict__ gw2, const float* __restrict__ gb2,
           const float* __restrict__ geps, int li,
           float* __restrict__ zout, int oGs) {
    __shared__ float zl[64], tl[64];
    int g = blockIdx.y, m = blockIdx.x, n = threadIdx.x;
    const float* Crow = C + (size_t)g * NN * NN + (size_t)m * NN;
    const float* h = hin + (size_t)g * hGs;
    float acc = 0.0f;
#pragma unroll 4
    for (int k = 0; k < NN; k++) acc += Crow[k] * h[k * F + n];
    acc += (1.0f + geps[li]) * h[m * F + n];
    zl[n] = acc;
    __syncthreads();
    const float* W1 = gw1 + (size_t)li * F * F;
    const float* W2 = gw2 + (size_t)li * F * F;
    float t = gb1[li * F + n];
#pragma unroll 4
    for (int k = 0; k < F; k++) t += zl[k] * W1[k * F + n];
    t = fmaxf(t, 0.0f);
    tl[n] = t;
    __syncthreads();
    float o = gb2[li * F + n];
#pragma unroll 4
    for (int k = 0; k < F; k++) o += tl[k] * W2[k * F + n];
    zout[(size_t)g * oGs + m * F + n] = o;
}

__global__ __launch_bounds__(256)
void k_bn(float* __restrict__ hsb, int hsGs, float* __restrict__ hbuf, int hGs,
          const float* __restrict__ gamma, const float* __restrict__ beta) {
    __shared__ float red[4][64];
    int g = blockIdx.x;
    float* z = hsb + (size_t)g * hsGs;
    float* h = hbuf + (size_t)g * hGs;
    int c = threadIdx.x & 63, rq = threadIdx.x >> 6;
    int r0 = rq * 96;
    float s = 0.0f;
    for (int r = r0; r < r0 + 96; r++) s += z[r * F + c];
    red[rq][c] = s;
    __syncthreads();
    float mu = (red[0][c] + red[1][c] + red[2][c] + red[3][c]) * (1.0f / NN);
    __syncthreads();
    float v = 0.0f;
    for (int r = r0; r < r0 + 96; r++) { float d = z[r * F + c] - mu; v += d * d; }
    red[rq][c] = v;
    __syncthreads();
    float var = (red[0][c] + red[1][c] + red[2][c] + red[3][c]) * (1.0f / NN);
    float is = rsqrtf(var + 1e-5f);
    float ga = gamma[c], be = beta[c];
    for (int r = r0; r < r0 + 96; r++) {
        float zn = (z[r * F + c] - mu) * is * ga + be;
        z[r * F + c] = zn;
        h[r * F + c] = fmaxf(zn, 0.0f);
    }
}

// f32 HS (graph 1 only) -> bf16 hi/lo
__global__ void k_cvt2(const float* __restrict__ HS, uint16_t* __restrict__ hhi,
                       uint16_t* __restrict__ hlo) {
    int idx = blockIdx.x * 256 + threadIdx.x;
    if (idx >= 6 * NN * F) return;
    float v = HS[idx];
    uint16_t h = f2bf(v);
    hhi[idx] = h;
    hlo[idx] = f2bf(v - bf2f(h));
}

__global__ __launch_bounds__(64)
void k_gedT2(const float* __restrict__ ged, uint16_t* __restrict__ ghi,
             uint16_t* __restrict__ glo) {
    __shared__ float t[64 * 65];
    int lk = blockIdx.x, lane = threadIdx.x;
    const float* src = ged + (size_t)lk * 4096;
    for (int d = 0; d < 64; d++) t[lane * 65 + d] = src[d * 64 + lane];
    __syncthreads();
    for (int e = 0; e < 64; e++) {
        float v = t[e * 65 + lane];
        uint16_t h = f2bf(v);
        ghi[(size_t)lk * 4096 + e * 64 + lane] = h;
        glo[(size_t)lk * 4096 + e * 64 + lane] = f2bf(v - bf2f(h));
    }
}

// wpack (f32):
// [0    wih 3072][3072 whh 3072][6144 wawT 1024][7168 vwT 1024]
// [8192 bR 32][8224 bZ 32][8256 biN 32][8288 bhN 32]
// [8320 wab 32][8352 vat 32][8384 vb 32]   total 8416
__global__ __launch_bounds__(256)
void k_wprep4(const float* __restrict__ wih, const float* __restrict__ whh,
              const float* __restrict__ waw, const float* __restrict__ vw,
              const float* __restrict__ bih, const float* __restrict__ bhh,
              const float* __restrict__ wab, const float* __restrict__ vat,
              const float* __restrict__ vb, float* __restrict__ wp) {
    int t = threadIdx.x;
    for (int idx = t; idx < 3072; idx += 256) {
        wp[idx] = wih[idx];
        wp[3072 + idx] = whh[idx];
    }
    for (int idx = t; idx < 1024; idx += 256) {
        int c = idx >> 5, k = idx & 31;
        wp[6144 + idx] = waw[k * 32 + c];
        wp[7168 + idx] = vw[k * 32 + c];
    }
    if (t < 64) wp[8192 + t] = bih[t] + bhh[t];
    if (t < 32) {
        wp[8256 + t] = bih[64 + t];
        wp[8288 + t] = bhh[64 + t];
        wp[8320 + t] = wab[t];
        wp[8352 + t] = vat[t];
        wp[8384 + t] = vb[t];
    }
}

// T1f[l,i,n=k*64+e] = sum_d gedT[l,n,d]*h1[l,i,d]  (hi/lo MFMA, f32 out)
__global__ __launch_bounds__(256)
void k_t1m2(const uint16_t* __restrict__ gThi, const uint16_t* __restrict__ gTlo,
            const uint16_t* __restrict__ hbhi, const uint16_t* __restrict__ hblo,
            float* __restrict__ T1f) {
    int l = blockIdx.z;
    int w = threadIdx.x >> 6, lane = threadIdx.x & 63;
    int nb = blockIdx.x * 128 + (w >> 1) * 64;
    int ib = blockIdx.y * 128 + (w & 1) * 64;
    int lr = lane & 15, lq = lane >> 4;
    const uint16_t* gah = gThi + (size_t)l * 2048 * 64;
    const uint16_t* gal = gTlo + (size_t)l * 2048 * 64;
    const uint16_t* gbh = hbhi + (size_t)l * NN * F;
    const uint16_t* gbl = hblo + (size_t)l * NN * F;
    shortx8 Ah[4][2], Al[4][2];
#pragma unroll
    for (int s = 0; s < 4; s++)
#pragma unroll
        for (int ks = 0; ks < 2; ks++) {
            size_t off = (size_t)(nb + s * 16 + lr) * 64 + ks * 32 + lq * 8;
            Ah[s][ks] = *reinterpret_cast<const shortx8*>(gah + off);
            Al[s][ks] = *reinterpret_cast<const shortx8*>(gal + off);
        }
#pragma unroll
    for (int si = 0; si < 4; si++) {
        shortx8 Bh[2], Bl[2];
#pragma unroll
        for (int ks = 0; ks < 2; ks++) {
            size_t off = (size_t)(ib + si * 16 + lr) * 64 + ks * 32 + lq * 8;
            Bh[ks] = *reinterpret_cast<const shortx8*>(gbh + off);
            Bl[ks] = *reinterpret_cast<const shortx8*>(gbl + off);
        }
#pragma unroll
        for (int sn = 0; sn < 4; sn++) {
            floatx4 a = (floatx4){0.f, 0.f, 0.f, 0.f};
#pragma unroll
            for (int ks = 0; ks < 2; ks++) {
                a = __builtin_amdgcn_mfma_f32_16x16x32_bf16(Ah[sn][ks], Bh[ks], a, 0, 0, 0);
                a = __builtin_amdgcn_mfma_f32_16x16x32_bf16(Ah[sn][ks], Bl[ks], a, 0, 0, 0);
                a = __builtin_amdgcn_mfma_f32_16x16x32_bf16(Al[sn][ks], Bh[ks], a, 0, 0, 0);
            }
            size_t addr = ((size_t)l * NN + (ib + si * 16 + lr)) * 2048 + (nb + sn * 16 + lq * 4);
            *reinterpret_cast<floatx4*>(T1f + addr) = a;
        }
    }
}

#define DOT4(W, A, B4) ((A)[4*(B4)+0]*(W)[0] + (A)[4*(B4)+1]*(W)[1] + \
                        (A)[4*(B4)+2]*(W)[2] + (A)[4*(B4)+3]*(W)[3])

// Block = 256 threads = 256 consecutive pairs (spans <=2 i values); grid 576.
// Per thread: 1 pair, all state in registers. __launch_bounds__(256,2):
// VGPR budget 256 -> no spills (the (256,3)/170-cap variant collapsed to
// 84 VGPRs and 9.7 GB of scratch traffic).
__global__ __launch_bounds__(256, 2)
void k_mega8(const float* __restrict__ T1f, const float* __restrict__ HS2,
             const float* __restrict__ wpack,
             const float* __restrict__ q1w, const float* __restrict__ q1b,
             const float* __restrict__ q2w, const float* __restrict__ q2b,
             const float* __restrict__ kw, const float* __restrict__ kb,
             float* __restrict__ out) {
    __shared__ float wl[8416];
    __shared__ float t1l[2][2048];
    const int TX = threadIdx.x;
    const int p0 = blockIdx.x * 256;
    const int p = p0 + TX;
    const int i = p / NN;
    const int j = p - i * NN;
    const int i0 = p0 / NN;
    const float* t1p = t1l[i - i0];   // wave-uniform (384 % 64 == 0)

    for (int idx = TX; idx < 8416; idx += 256) wl[idx] = wpack[idx];

#define FILL_T1(LL) do {                                                       \
    __syncthreads();                                                           \
    _Pragma("unroll")                                                          \
    for (int t = 0; t < 2; t++) {                                              \
        int it = i0 + t; if (it > NN - 1) it = NN - 1;                         \
        const float4* srcp = reinterpret_cast<const float4*>(                  \
            T1f + ((size_t)(LL) * NN + it) * 2048);                            \
        for (int idx = TX; idx < 512; idx += 256)                              \
            reinterpret_cast<float4*>(t1l[t])[idx] = srcp[idx];                \
    }                                                                          \
    __syncthreads();                                                           \
} while (0)

#define COMPUTE_X8(LL) do {                                                    \
    _Pragma("unroll") for (int k = 0; k < KD; k++) x[k] = 0.0f;                \
    const float4* hp = reinterpret_cast<const float4*>(                        \
        HS2 + ((size_t)(LL) * NN + j) * 64);                                   \
    _Pragma("unroll 2")                                                        \
    for (int eb = 0; eb < 16; eb++) {                                          \
        float4 a4 = hp[eb];                                                    \
        _Pragma("unroll") for (int k = 0; k < KD; k++) {                       \
            floatx4 t4 = *reinterpret_cast<const floatx4*>(t1p + k * 64 + eb * 4); \
            x[k] += t4[0]*a4.x + t4[1]*a4.y + t4[2]*a4.z + t4[3]*a4.w;         \
        }                                                                      \
    }                                                                          \
} while (0)

    float h[KD], pacc[KD];
#pragma unroll
    for (int k = 0; k < KD; k++) { h[k] = 0.0f; pacc[k] = 0.0f; }
    float sm = -1e30f, sden = 0.0f;

    // ================= phase A: GRU + layer attention =================
#pragma unroll 1
    for (int l = 0; l < 6; l++) {
        FILL_T1(l);
        float x[KD];
        COMPUTE_X8(l);
        float hnew[KD];
#pragma unroll
        for (int g = 0; g < KD; g++) {
            const floatx4* wiR = reinterpret_cast<const floatx4*>(wl + g * 32);
            const floatx4* wiZ = reinterpret_cast<const floatx4*>(wl + 1024 + g * 32);
            const floatx4* wiN = reinterpret_cast<const floatx4*>(wl + 2048 + g * 32);
            const floatx4* whR = reinterpret_cast<const floatx4*>(wl + 3072 + g * 32);
            const floatx4* whZ = reinterpret_cast<const floatx4*>(wl + 4096 + g * 32);
            const floatx4* whN = reinterpret_cast<const floatx4*>(wl + 5120 + g * 32);
            float ir = 0, iz = 0, in2 = 0, hr = 0, hz = 0, hn = 0;
#pragma unroll
            for (int k4 = 0; k4 < 8; k4++) {
                floatx4 w;
                w = wiR[k4]; ir  += DOT4(w, x, k4);
                w = wiZ[k4]; iz  += DOT4(w, x, k4);
                w = wiN[k4]; in2 += DOT4(w, x, k4);
                w = whR[k4]; hr  += DOT4(w, h, k4);
                w = whZ[k4]; hz  += DOT4(w, h, k4);
                w = whN[k4]; hn  += DOT4(w, h, k4);
            }
            float r  = sigm(ir + hr + wl[8192 + g]);
            float zg = sigm(iz + hz + wl[8224 + g]);
            float ng = tanhf_(in2 + wl[8256 + g] + r * (hn + wl[8288 + g]));
            hnew[g] = (1.0f - zg) * ng + zg * h[g];
        }
#pragma unroll
        for (int k = 0; k < KD; k++) h[k] = hnew[k];
        // attention score
        float sc = 0.0f;
#pragma unroll 2
        for (int c = 0; c < KD; c++) {
            const floatx4* wr = reinterpret_cast<const floatx4*>(wl + 6144 + c * 32);
            float t = wl[8320 + c];
#pragma unroll
            for (int k4 = 0; k4 < 8; k4++) {
                floatx4 w = wr[k4];
                t += DOT4(w, h, k4);
            }
            sc += tanhf_(t) * wl[8352 + c];
        }
        float nm = fmaxf(sm, sc);
        float eo = __expf(sm - nm), en = __expf(sc - nm);
        sden = sden * eo + en; sm = nm;
#pragma unroll
        for (int k = 0; k < KD; k++) pacc[k] = pacc[k] * eo + en * h[k];
    }

    // ---------------- pattern -> q -> qk ----------------
    float qk[KD], qd;
    {
        float inv = 1.0f / sden;
#pragma unroll
        for (int k = 0; k < KD; k++) pacc[k] *= inv;
        float t1r[KD];
#pragma unroll
        for (int c = 0; c < KD; c++) {
            float t = q1b[c];
#pragma unroll
            for (int k = 0; k < KD; k++) t += pacc[k] * q1w[k * KD + c];
            t1r[c] = fmaxf(t, 0.0f);
        }
        float q[KD];
#pragma unroll
        for (int c = 0; c < KD; c++) {
            float t = q2b[c];
#pragma unroll
            for (int k = 0; k < KD; k++) t += t1r[k] * q2w[k * KD + c];
            q[c] = t;
        }
        qd = 0.0f;
#pragma unroll
        for (int c = 0; c < KD; c++) qd += q[c] * kb[c];
#pragma unroll
        for (int k = 0; k < KD; k++) {
            float t = 0.0f;
#pragma unroll
            for (int c = 0; c < KD; c++) t += q[c] * kw[k * KD + c];
            qk[k] = t;
        }
    }

    // ================= phase B: scores + context =================
    float ctx[KD];
#pragma unroll
    for (int k = 0; k < KD; k++) ctx[k] = 0.0f;
    float s2m = -1e30f, s2d = 0.0f;
#pragma unroll 1
    for (int l = 0; l < 6; l++) {
        FILL_T1(l);
        float x[KD];
        COMPUTE_X8(l);
        float s = qd;
#pragma unroll
        for (int k = 0; k < KD; k++) s += x[k] * qk[k];
        s *= 0.17677669529663687f;
        float nm = fmaxf(s2m, s);
        float eo = __expf(s2m - nm), en = __expf(s - nm);
        s2d = s2d * eo + en; s2m = nm;
#pragma unroll 2
        for (int c = 0; c < KD; c++) {
            const floatx4* vr = reinterpret_cast<const floatx4*>(wl + 7168 + c * 32);
            float vc = wl[8384 + c];
#pragma unroll
            for (int k4 = 0; k4 < 8; k4++) {
                floatx4 w = vr[k4];
                vc += DOT4(w, x, k4);
            }
            ctx[c] = ctx[c] * eo + en * vc;
        }
    }
    float invd = 1.0f / s2d;
    float* op = out + ((size_t)i * NN + j) * KD;
#pragma unroll
    for (int k = 0; k < KD; k += 4) {
        float4 w4;
        w4.x = ctx[k] * invd; w4.y = ctx[k + 1] * invd;
        w4.z = ctx[k + 2] * invd; w4.w = ctx[k + 3] * invd;
        *reinterpret_cast<float4*>(op + k) = w4;
    }
#undef FILL_T1
#undef COMPUTE_X8
}

extern "C" void kernel_launch(void* const* d_in, const int* in_sizes, int n_in,
                              void* d_out, int out_size, void* d_ws, size_t ws_size,
                              hipStream_t stream) {
    const float* f1   = (const float*)d_in[0];
    const float* f2   = (const float*)d_in[1];
    const float* l0w1 = (const float*)d_in[2];
    const float* l0b1 = (const float*)d_in[3];
    const float* l0w2 = (const float*)d_in[4];
    const float* l0b2 = (const float*)d_in[5];
    const float* geps = (const float*)d_in[6];
    const float* gw1  = (const float*)d_in[7];
    const float* gb1  = (const float*)d_in[8];
    const float* gw2  = (const float*)d_in[9];
    const float* gb2  = (const float*)d_in[10];
    const float* gga  = (const float*)d_in[11];
    const float* gbe  = (const float*)d_in[12];
    const float* ged  = (const float*)d_in[13];
    const float* wih  = (const float*)d_in[14];
    const float* whh  = (const float*)d_in[15];
    const float* bih  = (const float*)d_in[16];
    const float* bhh  = (const float*)d_in[17];
    const float* waw  = (const float*)d_in[18];
    const float* wab  = (const float*)d_in[19];
    const float* vat  = (const float*)d_in[20];
    const float* q1w  = (const float*)d_in[21];
    const float* q1b  = (const float*)d_in[22];
    const float* q2w  = (const float*)d_in[23];
    const float* q2b  = (const float*)d_in[24];
    const float* kw   = (const float*)d_in[25];
    const float* kb   = (const float*)d_in[26];
    const float* vw   = (const float*)d_in[27];
    const float* vb   = (const float*)d_in[28];
    const int*   e1   = (const int*)d_in[29];
    const int*   e2   = (const int*)d_in[30];

    // ---- workspace layout ----
    float* C     = (float*)d_ws;                        // 2*NN*NN
    float* Adj   = C + (size_t)2 * NN * NN;
    float* X     = Adj + (size_t)2 * NN * NN;           // 2*NN*33
    float* H     = X + (size_t)2 * NN * 33;             // 2*NN*F
    float* HS    = H + (size_t)2 * NN * F;              // [2][6][NN][F]
    float* T1f   = HS + (size_t)2 * 6 * NN * F;         // 6*NN*2048
    float* wpack = T1f + (size_t)6 * NN * 2048;         // 8416
    uint16_t* hbhi = (uint16_t*)(wpack + 8448);         // 6*NN*F
    uint16_t* hblo = hbhi + (size_t)6 * NN * F;
    uint16_t* gThi = hblo + (size_t)6 * NN * F;         // 6*2048*64
    uint16_t* gTlo = gThi + (size_t)6 * 2048 * 64;
    float* out = (float*)d_out;

    const int GHS = 6 * NN * F;
    const int GH  = NN * F;

    k_zero<<<576, 256, 0, stream>>>(C, 4 * NN * NN);
    k_build<<<(2 * NE + 255) / 256, 256, 0, stream>>>(e1, e2, C, Adj);
    k_degx<<<dim3(6, 2), 64, 0, stream>>>(f1, f2, Adj, X);
    k_lin0<<<dim3(NN, 2), 64, 0, stream>>>(X, l0w1, l0b1, l0w2, l0b2, HS);
    for (int li = 0; li < 5; li++) {
        const float* hp = (li == 0) ? HS : H;
        int hGs = (li == 0) ? GHS : GH;
        k_gin<<<dim3(NN, 2), 64, 0, stream>>>(C, hp, hGs, gw1, gb1, gw2, gb2,
                                              geps, li, HS + (li + 1) * GH, GHS);
        k_bn<<<2, 256, 0, stream>>>(HS + (li + 1) * GH, GHS, H, GH,
                                    gga + li * F, gbe + li * F);
    }
    k_cvt2<<<(6 * NN * F + 255) / 256, 256, 0, stream>>>(HS, hbhi, hblo);
    k_gedT2<<<6 * KD, 64, 0, stream>>>(ged, gThi, gTlo);
    k_wprep4<<<1, 256, 0, stream>>>(wih, whh, waw, vw, bih, bhh, wab, vat, vb, wpack);
    k_t1m2<<<dim3(16, 3, 6), 256, 0, stream>>>(gThi, gTlo, hbhi, hblo, T1f);
    k_mega8<<<dim3(576), 256, 0, stream>>>(T1f, HS + GHS, wpack,
                                           q1w, q1b, q2w, q2b, kw, kb, out);
}

// Round 9
// 2049.679 us; speedup vs baseline: 2.7695x; 1.8805x over previous
//
#include <hip/hip_runtime.h>
#include <stdint.h>

#define NN 384
#define NE 3456
#define NLb 32
#define F 64
#define KD 32

typedef short shortx8 __attribute__((ext_vector_type(8)));
typedef float floatx4 __attribute__((ext_vector_type(4)));

__device__ __forceinline__ float sigm(float v) { return 1.0f / (1.0f + __expf(-v)); }
__device__ __forceinline__ float tanhf_(float v) {
    float x = fminf(fmaxf(v, -15.0f), 15.0f);
    float e = __expf(2.0f * x);
    return (e - 1.0f) / (e + 1.0f);
}
__device__ __forceinline__ uint16_t f2bf(float f) {
    uint32_t u = __float_as_uint(f);
    uint32_t r = (u + 0x7fffu + ((u >> 16) & 1u)) >> 16;
    return (uint16_t)r;
}
__device__ __forceinline__ float bf2f(uint16_t h) {
    return __uint_as_float((uint32_t)h << 16);
}

__global__ void k_zero(float* p, int n) {
    int i = blockIdx.x * 256 + threadIdx.x;
    int st = gridDim.x * 256;
    for (; i < n; i += st) p[i] = 0.0f;
}

__global__ void k_build(const int* __restrict__ e1, const int* __restrict__ e2,
                        float* __restrict__ C, float* __restrict__ Adj) {
    int t = blockIdx.x * 256 + threadIdx.x;
    if (t >= 2 * NE) return;
    int g = t / NE, e = t % NE;
    const int* ei = g ? e2 : e1;
    int s = ei[e], d = ei[NE + e];
    atomicAdd(&C[(size_t)g * NN * NN + d * NN + s], 1.0f);
    if (e < NE - NN) Adj[(size_t)g * NN * NN + s * NN + d] = 1.0f;
}

__global__ void k_degx(const float* __restrict__ f1, const float* __restrict__ f2,
                       const float* __restrict__ Adj, float* __restrict__ X) {
    int g = blockIdx.y;
    int s = blockIdx.x * 64 + threadIdx.x;
    const float* feats = g ? f2 : f1;
    const float* A = Adj + (size_t)g * NN * NN;
    float* Xg = X + (size_t)g * NN * 33;
    float deg = 0.0f;
    for (int d = 0; d < NN; d++) deg += A[s * NN + d];
    for (int c = 0; c < NLb; c++) Xg[s * 33 + c] = feats[s * NLb + c];
    Xg[s * 33 + 32] = deg;
}

__global__ __launch_bounds__(64)
void k_lin0(const float* __restrict__ X, const float* __restrict__ w1,
            const float* __restrict__ b1, const float* __restrict__ w2,
            const float* __restrict__ b2, float* __restrict__ HS) {
    __shared__ float tl[64];
    int g = blockIdx.y, m = blockIdx.x, n = threadIdx.x;
    const float* Xr = X + (size_t)g * NN * 33 + m * 33;
    float t = b1[n];
#pragma unroll
    for (int k = 0; k < 33; k++) t += Xr[k] * w1[k * F + n];
    t = fmaxf(t, 0.0f);
    tl[n] = t;
    __syncthreads();
    float o = b2[n];
#pragma unroll 4
    for (int k = 0; k < F; k++) o += tl[k] * w2[k * F + n];
    HS[(size_t)g * (6 * NN * F) + m * F + n] = o;
}

__global__ __launch_bounds__(64)
void k_gin(const float* __restrict__ C, const float* __restrict__ hin, int hGs,
           const float* __restrict__ gw1, const float* __restrict__ gb1,
           const float* __restrict__ gw2, const float* __restrict__ gb2,
           const float* __restrict__ geps, int li,
           float* __restrict__ zout, int oGs) {
    __shared__ float zl[64], tl[64];
    int g = blockIdx.y, m = blockIdx.x, n = threadIdx.x;
    const float* Crow = C + (size_t)g * NN * NN + (size_t)m * NN;
    const float* h = hin + (size_t)g * hGs;
    float acc = 0.0f;
#pragma unroll 4
    for (int k = 0; k < NN; k++) acc += Crow[k] * h[k * F + n];
    acc += (1.0f + geps[li]) * h[m * F + n];
    zl[n] = acc;
    __syncthreads();
    const float* W1 = gw1 + (size_t)li * F * F;
    const float* W2 = gw2 + (size_t)li * F * F;
    float t = gb1[li * F + n];
#pragma unroll 4
    for (int k = 0; k < F; k++) t += zl[k] * W1[k * F + n];
    t = fmaxf(t, 0.0f);
    tl[n] = t;
    __syncthreads();
    float o = gb2[li * F + n];
#pragma unroll 4
    for (int k = 0; k < F; k++) o += tl[k] * W2[k * F + n];
    zout[(size_t)g * oGs + m * F + n] = o;
}

__global__ __launch_bounds__(256)
void k_bn(float* __restrict__ hsb, int hsGs, float* __restrict__ hbuf, int hGs,
          const float* __restrict__ gamma, const float* __restrict__ beta) {
    __shared__ float red[4][64];
    int g = blockIdx.x;
    float* z = hsb + (size_t)g * hsGs;
    float* h = hbuf + (size_t)g * hGs;
    int c = threadIdx.x & 63, rq = threadIdx.x >> 6;
    int r0 = rq * 96;
    float s = 0.0f;
    for (int r = r0; r < r0 + 96; r++) s += z[r * F + c];
    red[rq][c] = s;
    __syncthreads();
    float mu = (red[0][c] + red[1][c] + red[2][c] + red[3][c]) * (1.0f / NN);
    __syncthreads();
    float v = 0.0f;
    for (int r = r0; r < r0 + 96; r++) { float d = z[r * F + c] - mu; v += d * d; }
    red[rq][c] = v;
    __syncthreads();
    float var = (red[0][c] + red[1][c] + red[2][c] + red[3][c]) * (1.0f / NN);
    float is = rsqrtf(var + 1e-5f);
    float ga = gamma[c], be = beta[c];
    for (int r = r0; r < r0 + 96; r++) {
        float zn = (z[r * F + c] - mu) * is * ga + be;
        z[r * F + c] = zn;
        h[r * F + c] = fmaxf(zn, 0.0f);
    }
}

// f32 HS (graph 1 only) -> bf16 hi/lo
__global__ void k_cvt2(const float* __restrict__ HS, uint16_t* __restrict__ hhi,
                       uint16_t* __restrict__ hlo) {
    int idx = blockIdx.x * 256 + threadIdx.x;
    if (idx >= 6 * NN * F) return;
    float v = HS[idx];
    uint16_t h = f2bf(v);
    hhi[idx] = h;
    hlo[idx] = f2bf(v - bf2f(h));
}

__global__ __launch_bounds__(64)
void k_gedT2(const float* __restrict__ ged, uint16_t* __restrict__ ghi,
             uint16_t* __restrict__ glo) {
    __shared__ float t[64 * 65];
    int lk = blockIdx.x, lane = threadIdx.x;
    const float* src = ged + (size_t)lk * 4096;
    for (int d = 0; d < 64; d++) t[lane * 65 + d] = src[d * 64 + lane];
    __syncthreads();
    for (int e = 0; e < 64; e++) {
        float v = t[e * 65 + lane];
        uint16_t h = f2bf(v);
        ghi[(size_t)lk * 4096 + e * 64 + lane] = h;
        glo[(size_t)lk * 4096 + e * 64 + lane] = f2bf(v - bf2f(h));
    }
}

// wpack (f32):
// [0    wih 3072][3072 whh 3072][6144 wawT 1024][7168 vwT 1024]
// [8192 bR 32][8224 bZ 32][8256 biN 32][8288 bhN 32]
// [8320 wab 32][8352 vat 32][8384 vb 32]   total 8416
__global__ __launch_bounds__(256)
void k_wprep4(const float* __restrict__ wih, const float* __restrict__ whh,
              const float* __restrict__ waw, const float* __restrict__ vw,
              const float* __restrict__ bih, const float* __restrict__ bhh,
              const float* __restrict__ wab, const float* __restrict__ vat,
              const float* __restrict__ vb, float* __restrict__ wp) {
    int t = threadIdx.x;
    for (int idx = t; idx < 3072; idx += 256) {
        wp[idx] = wih[idx];
        wp[3072 + idx] = whh[idx];
    }
    for (int idx = t; idx < 1024; idx += 256) {
        int c = idx >> 5, k = idx & 31;
        wp[6144 + idx] = waw[k * 32 + c];
        wp[7168 + idx] = vw[k * 32 + c];
    }
    if (t < 64) wp[8192 + t] = bih[t] + bhh[t];
    if (t < 32) {
        wp[8256 + t] = bih[64 + t];
        wp[8288 + t] = bhh[64 + t];
        wp[8320 + t] = wab[t];
        wp[8352 + t] = vat[t];
        wp[8384 + t] = vb[t];
    }
}

// T1f[l,i,n=k*64+e] = sum_d gedT[l,n,d]*h1[l,i,d]  (hi/lo MFMA, f32 out)
__global__ __launch_bounds__(256)
void k_t1m2(const uint16_t* __restrict__ gThi, const uint16_t* __restrict__ gTlo,
            const uint16_t* __restrict__ hbhi, const uint16_t* __restrict__ hblo,
            float* __restrict__ T1f) {
    int l = blockIdx.z;
    int w = threadIdx.x >> 6, lane = threadIdx.x & 63;
    int nb = blockIdx.x * 128 + (w >> 1) * 64;
    int ib = blockIdx.y * 128 + (w & 1) * 64;
    int lr = lane & 15, lq = lane >> 4;
    const uint16_t* gah = gThi + (size_t)l * 2048 * 64;
    const uint16_t* gal = gTlo + (size_t)l * 2048 * 64;
    const uint16_t* gbh = hbhi + (size_t)l * NN * F;
    const uint16_t* gbl = hblo + (size_t)l * NN * F;
    shortx8 Ah[4][2], Al[4][2];
#pragma unroll
    for (int s = 0; s < 4; s++)
#pragma unroll
        for (int ks = 0; ks < 2; ks++) {
            size_t off = (size_t)(nb + s * 16 + lr) * 64 + ks * 32 + lq * 8;
            Ah[s][ks] = *reinterpret_cast<const shortx8*>(gah + off);
            Al[s][ks] = *reinterpret_cast<const shortx8*>(gal + off);
        }
#pragma unroll
    for (int si = 0; si < 4; si++) {
        shortx8 Bh[2], Bl[2];
#pragma unroll
        for (int ks = 0; ks < 2; ks++) {
            size_t off = (size_t)(ib + si * 16 + lr) * 64 + ks * 32 + lq * 8;
            Bh[ks] = *reinterpret_cast<const shortx8*>(gbh + off);
            Bl[ks] = *reinterpret_cast<const shortx8*>(gbl + off);
        }
#pragma unroll
        for (int sn = 0; sn < 4; sn++) {
            floatx4 a = (floatx4){0.f, 0.f, 0.f, 0.f};
#pragma unroll
            for (int ks = 0; ks < 2; ks++) {
                a = __builtin_amdgcn_mfma_f32_16x16x32_bf16(Ah[sn][ks], Bh[ks], a, 0, 0, 0);
                a = __builtin_amdgcn_mfma_f32_16x16x32_bf16(Ah[sn][ks], Bl[ks], a, 0, 0, 0);
                a = __builtin_amdgcn_mfma_f32_16x16x32_bf16(Al[sn][ks], Bh[ks], a, 0, 0, 0);
            }
            size_t addr = ((size_t)l * NN + (ib + si * 16 + lr)) * 2048 + (nb + sn * 16 + lq * 4);
            *reinterpret_cast<floatx4*>(T1f + addr) = a;
        }
    }
}

#define DOT4(W, A, B4) ((A)[4*(B4)+0]*(W)[0] + (A)[4*(B4)+1]*(W)[1] + \
                        (A)[4*(B4)+2]*(W)[2] + (A)[4*(B4)+3]*(W)[3])

// Block = 192 threads = half an i-row (384 = 2*192 -> single i per block).
// Grid 768. LDS = 33.7KB weights + 8KB T1 tile = 41.7KB -> 3 blocks/CU by LDS.
// (192,1) launch bounds: the ONLY config measured spill-free (mega7: 196 VGPR).
__global__ __launch_bounds__(192, 1)
void k_mega9(const float* __restrict__ T1f, const float* __restrict__ HS2,
             const float* __restrict__ wpack,
             const float* __restrict__ q1w, const float* __restrict__ q1b,
             const float* __restrict__ q2w, const float* __restrict__ q2b,
             const float* __restrict__ kw, const float* __restrict__ kb,
             float* __restrict__ out) {
    __shared__ float wl[8416];
    __shared__ float t1l[2048];
    const int TX = threadIdx.x;
    const int b = blockIdx.x;
    const int i = b >> 1;
    const int j = (b & 1) * 192 + TX;

    for (int idx = TX; idx < 8416; idx += 192) wl[idx] = wpack[idx];

#define FILL_T1(LL) do {                                                       \
    __syncthreads();                                                           \
    const float4* srcp = reinterpret_cast<const float4*>(                      \
        T1f + ((size_t)(LL) * NN + i) * 2048);                                 \
    for (int idx = TX; idx < 512; idx += 192)                                  \
        reinterpret_cast<float4*>(t1l)[idx] = srcp[idx];                       \
    __syncthreads();                                                           \
} while (0)

#define COMPUTE_X9(LL) do {                                                    \
    _Pragma("unroll") for (int k = 0; k < KD; k++) x[k] = 0.0f;                \
    const float4* hp = reinterpret_cast<const float4*>(                        \
        HS2 + ((size_t)(LL) * NN + j) * 64);                                   \
    _Pragma("unroll 2")                                                        \
    for (int eb = 0; eb < 16; eb++) {                                          \
        float4 a4 = hp[eb];                                                    \
        _Pragma("unroll") for (int k = 0; k < KD; k++) {                       \
            floatx4 t4 = *reinterpret_cast<const floatx4*>(t1l + k * 64 + eb * 4); \
            x[k] += t4[0]*a4.x + t4[1]*a4.y + t4[2]*a4.z + t4[3]*a4.w;         \
        }                                                                      \
    }                                                                          \
} while (0)

    float h[KD], pacc[KD];
#pragma unroll
    for (int k = 0; k < KD; k++) { h[k] = 0.0f; pacc[k] = 0.0f; }
    float sm = -1e30f, sden = 0.0f;

    // ================= phase A: GRU + layer attention =================
#pragma unroll 1
    for (int l = 0; l < 6; l++) {
        FILL_T1(l);
        float x[KD];
        COMPUTE_X9(l);
        float hnew[KD];
#pragma unroll
        for (int g = 0; g < KD; g++) {
            const floatx4* wiR = reinterpret_cast<const floatx4*>(wl + g * 32);
            const floatx4* wiZ = reinterpret_cast<const floatx4*>(wl + 1024 + g * 32);
            const floatx4* wiN = reinterpret_cast<const floatx4*>(wl + 2048 + g * 32);
            const floatx4* whR = reinterpret_cast<const floatx4*>(wl + 3072 + g * 32);
            const floatx4* whZ = reinterpret_cast<const floatx4*>(wl + 4096 + g * 32);
            const floatx4* whN = reinterpret_cast<const floatx4*>(wl + 5120 + g * 32);
            float ir = 0, iz = 0, in2 = 0, hr = 0, hz = 0, hn = 0;
#pragma unroll
            for (int k4 = 0; k4 < 8; k4++) {
                floatx4 w;
                w = wiR[k4]; ir  += DOT4(w, x, k4);
                w = wiZ[k4]; iz  += DOT4(w, x, k4);
                w = wiN[k4]; in2 += DOT4(w, x, k4);
                w = whR[k4]; hr  += DOT4(w, h, k4);
                w = whZ[k4]; hz  += DOT4(w, h, k4);
                w = whN[k4]; hn  += DOT4(w, h, k4);
            }
            float r  = sigm(ir + hr + wl[8192 + g]);
            float zg = sigm(iz + hz + wl[8224 + g]);
            float ng = tanhf_(in2 + wl[8256 + g] + r * (hn + wl[8288 + g]));
            hnew[g] = (1.0f - zg) * ng + zg * h[g];
        }
#pragma unroll
        for (int k = 0; k < KD; k++) h[k] = hnew[k];
        // attention score
        float sc = 0.0f;
#pragma unroll 2
        for (int c = 0; c < KD; c++) {
            const floatx4* wr = reinterpret_cast<const floatx4*>(wl + 6144 + c * 32);
            float t = wl[8320 + c];
#pragma unroll
            for (int k4 = 0; k4 < 8; k4++) {
                floatx4 w = wr[k4];
                t += DOT4(w, h, k4);
            }
            sc += tanhf_(t) * wl[8352 + c];
        }
        float nm = fmaxf(sm, sc);
        float eo = __expf(sm - nm), en = __expf(sc - nm);
        sden = sden * eo + en; sm = nm;
#pragma unroll
        for (int k = 0; k < KD; k++) pacc[k] = pacc[k] * eo + en * h[k];
    }

    // ---------------- pattern -> q -> qk ----------------
    float qk[KD], qd;
    {
        float inv = 1.0f / sden;
#pragma unroll
        for (int k = 0; k < KD; k++) pacc[k] *= inv;
        float t1r[KD];
#pragma unroll
        for (int c = 0; c < KD; c++) {
            float t = q1b[c];
#pragma unroll
            for (int k = 0; k < KD; k++) t += pacc[k] * q1w[k * KD + c];
            t1r[c] = fmaxf(t, 0.0f);
        }
        float q[KD];
#pragma unroll
        for (int c = 0; c < KD; c++) {
            float t = q2b[c];
#pragma unroll
            for (int k = 0; k < KD; k++) t += t1r[k] * q2w[k * KD + c];
            q[c] = t;
        }
        qd = 0.0f;
#pragma unroll
        for (int c = 0; c < KD; c++) qd += q[c] * kb[c];
#pragma unroll
        for (int k = 0; k < KD; k++) {
            float t = 0.0f;
#pragma unroll
            for (int c = 0; c < KD; c++) t += q[c] * kw[k * KD + c];
            qk[k] = t;
        }
    }

    // ================= phase B: scores + context =================
    float ctx[KD];
#pragma unroll
    for (int k = 0; k < KD; k++) ctx[k] = 0.0f;
    float s2m = -1e30f, s2d = 0.0f;
#pragma unroll 1
    for (int l = 0; l < 6; l++) {
        FILL_T1(l);
        float x[KD];
        COMPUTE_X9(l);
        float s = qd;
#pragma unroll
        for (int k = 0; k < KD; k++) s += x[k] * qk[k];
        s *= 0.17677669529663687f;
        float nm = fmaxf(s2m, s);
        float eo = __expf(s2m - nm), en = __expf(s - nm);
        s2d = s2d * eo + en; s2m = nm;
#pragma unroll 2
        for (int c = 0; c < KD; c++) {
            const floatx4* vr = reinterpret_cast<const floatx4*>(wl + 7168 + c * 32);
            float vc = wl[8384 + c];
#pragma unroll
            for (int k4 = 0; k4 < 8; k4++) {
                floatx4 w = vr[k4];
                vc += DOT4(w, x, k4);
            }
            ctx[c] = ctx[c] * eo + en * vc;
        }
    }
    float invd = 1.0f / s2d;
    float* op = out + ((size_t)i * NN + j) * KD;
#pragma unroll
    for (int k = 0; k < KD; k += 4) {
        float4 w4;
        w4.x = ctx[k] * invd; w4.y = ctx[k + 1] * invd;
        w4.z = ctx[k + 2] * invd; w4.w = ctx[k + 3] * invd;
        *reinterpret_cast<float4*>(op + k) = w4;
    }
#undef FILL_T1
#undef COMPUTE_X9
}

extern "C" void kernel_launch(void* const* d_in, const int* in_sizes, int n_in,
                              void* d_out, int out_size, void* d_ws, size_t ws_size,
                              hipStream_t stream) {
    const float* f1   = (const float*)d_in[0];
    const float* f2   = (const float*)d_in[1];
    const float* l0w1 = (const float*)d_in[2];
    const float* l0b1 = (const float*)d_in[3];
    const float* l0w2 = (const float*)d_in[4];
    const float* l0b2 = (const float*)d_in[5];
    const float* geps = (const float*)d_in[6];
    const float* gw1  = (const float*)d_in[7];
    const float* gb1  = (const float*)d_in[8];
    const float* gw2  = (const float*)d_in[9];
    const float* gb2  = (const float*)d_in[10];
    const float* gga  = (const float*)d_in[11];
    const float* gbe  = (const float*)d_in[12];
    const float* ged  = (const float*)d_in[13];
    const float* wih  = (const float*)d_in[14];
    const float* whh  = (const float*)d_in[15];
    const float* bih  = (const float*)d_in[16];
    const float* bhh  = (const float*)d_in[17];
    const float* waw  = (const float*)d_in[18];
    const float* wab  = (const float*)d_in[19];
    const float* vat  = (const float*)d_in[20];
    const float* q1w  = (const float*)d_in[21];
    const float* q1b  = (const float*)d_in[22];
    const float* q2w  = (const float*)d_in[23];
    const float* q2b  = (const float*)d_in[24];
    const float* kw   = (const float*)d_in[25];
    const float* kb   = (const float*)d_in[26];
    const float* vw   = (const float*)d_in[27];
    const float* vb   = (const float*)d_in[28];
    const int*   e1   = (const int*)d_in[29];
    const int*   e2   = (const int*)d_in[30];

    // ---- workspace layout ----
    float* C     = (float*)d_ws;                        // 2*NN*NN
    float* Adj   = C + (size_t)2 * NN * NN;
    float* X     = Adj + (size_t)2 * NN * NN;           // 2*NN*33
    float* H     = X + (size_t)2 * NN * 33;             // 2*NN*F
    float* HS    = H + (size_t)2 * NN * F;              // [2][6][NN][F]
    float* T1f   = HS + (size_t)2 * 6 * NN * F;         // 6*NN*2048
    float* wpack = T1f + (size_t)6 * NN * 2048;         // 8416
    uint16_t* hbhi = (uint16_t*)(wpack + 8448);         // 6*NN*F
    uint16_t* hblo = hbhi + (size_t)6 * NN * F;
    uint16_t* gThi = hblo + (size_t)6 * NN * F;         // 6*2048*64
    uint16_t* gTlo = gThi + (size_t)6 * 2048 * 64;
    float* out = (float*)d_out;

    const int GHS = 6 * NN * F;
    const int GH  = NN * F;

    k_zero<<<576, 256, 0, stream>>>(C, 4 * NN * NN);
    k_build<<<(2 * NE + 255) / 256, 256, 0, stream>>>(e1, e2, C, Adj);
    k_degx<<<dim3(6, 2), 64, 0, stream>>>(f1, f2, Adj, X);
    k_lin0<<<dim3(NN, 2), 64, 0, stream>>>(X, l0w1, l0b1, l0w2, l0b2, HS);
    for (int li = 0; li < 5; li++) {
        const float* hp = (li == 0) ? HS : H;
        int hGs = (li == 0) ? GHS : GH;
        k_gin<<<dim3(NN, 2), 64, 0, stream>>>(C, hp, hGs, gw1, gb1, gw2, gb2,
                                              geps, li, HS + (li + 1) * GH, GHS);
        k_bn<<<2, 256, 0, stream>>>(HS + (li + 1) * GH, GHS, H, GH,
                                    gga + li * F, gbe + li * F);
    }
    k_cvt2<<<(6 * NN * F + 255) / 256, 256, 0, stream>>>(HS, hbhi, hblo);
    k_gedT2<<<6 * KD, 64, 0, stream>>>(ged, gThi, gTlo);
    k_wprep4<<<1, 256, 0, stream>>>(wih, whh, waw, vw, bih, bhh, wab, vat, vb, wpack);
    k_t1m2<<<dim3(16, 3, 6), 256, 0, stream>>>(gThi, gTlo, hbhi, hblo, T1f);
    k_mega9<<<dim3(768), 192, 0, stream>>>(T1f, HS + GHS, wpack,
                                           q1w, q1b, q2w, q2b, kw, kb, out);
}